// Round 2
// baseline (532.764 us; speedup 1.0000x reference)
//
#include <hip/hip_runtime.h>
#include <hip/hip_bf16.h>

typedef unsigned short u16;
typedef unsigned int   u32;
typedef __attribute__((ext_vector_type(4))) float f32x4;
typedef __attribute__((ext_vector_type(8))) short s16x8;
typedef __attribute__((ext_vector_type(4))) u16 u16x4;

#define DI __device__ __forceinline__

static constexpr int Bb = 2, Ss = 2048, Hh = 16, Dd = 64, Ee = 1024;
static constexpr int Mrows = Bb * Ss;          // 4096
static constexpr size_t NE = (size_t)Mrows * Ee;   // 4 M elems
static constexpr size_t WN = (size_t)Ee * Ee;      // 1 M elems

DI float bf2f(u16 h) { u32 u = ((u32)h) << 16; return __builtin_bit_cast(float, u); }
DI u16 f2bf(float f) {
    u32 u = __builtin_bit_cast(u32, f);
    u32 r = (u + 0x7FFFu + ((u >> 16) & 1u)) >> 16;
    return (u16)r;
}

#define MFMA(a, b, c) __builtin_amdgcn_mfma_f32_16x16x32_bf16((a), (b), (c), 0, 0, 0)

// ---------------- prep: fp32 -> bf16 hi (+ optional lo residual) ----------------
__global__ __launch_bounds__(256) void k_split(const float* __restrict__ x,
                                               u16* __restrict__ h, u16* __restrict__ l, int n) {
    int i = blockIdx.x * 256 + threadIdx.x;
    if (i >= n) return;
    float v = x[i];
    u16 hh = f2bf(v);
    h[i] = hh;
    if (l) l[i] = f2bf(v - bf2f(hh));
}

// ---------------- prep: weights -> B^T form [N][K], bf16 hi (+lo) ----------------
__global__ __launch_bounds__(256) void k_wT(const float* __restrict__ W,
                                            u16* __restrict__ h, u16* __restrict__ l, int stacked) {
    int idx = blockIdx.x * 256 + threadIdx.x;   // n*1024 + k
    if (idx >= (int)WN) return;
    int n = idx >> 10, k = idx & 1023;
    float v = stacked ? W[(size_t)(n >> 6) * (Ee * Dd) + (size_t)k * Dd + (n & 63)]
                      : W[(size_t)k * Ee + n];
    u16 hh = f2bf(v);
    h[idx] = hh;
    if (l) l[idx] = f2bf(v - bf2f(hh));
}

// ---------------- GEMM: C[M][N] = A[M][K] * B^T[N][K] + bias[n] ----------------
// LDS rows: 128 x 32 u16 (4 chunks of 8). Swizzle: chunk' = chunk ^ ((row>>1)&3)
// -> fragment-read start banks = 16*(row&1) + 4*chunk' : 8 distinct x 2 lanes (free).
// SPLIT=1: hi/lo 3-MFMA accumulate. OUTMODE: 0=f32 row-major, 1=bf16 transposed, 2=bf16 hi/lo.
template <int SPLIT, int OUTMODE>
__global__ __launch_bounds__(256) void k_gemm(
    const u16* __restrict__ Ah, const u16* __restrict__ Al,
    const u16* __restrict__ Bh, const u16* __restrict__ Bl,
    const float* __restrict__ bias,
    u16* __restrict__ C16h, u16* __restrict__ C16l, float* __restrict__ Cf,
    int M, int N, int K) {
    constexpr int NB = SPLIT ? 2 : 1;
    __shared__ u16 As[NB][128 * 32];
    __shared__ u16 Bs[NB][128 * 32];

    const int tid = threadIdx.x;
    const int wave = tid >> 6, lane = tid & 63;
    const int quad = lane >> 4, l16 = lane & 15;
    const int m0 = blockIdx.y * 128, n0 = blockIdx.x * 128;
    const int wm = (wave >> 1) * 64, wn = (wave & 1) * 64;
    const int fsw = quad ^ ((l16 >> 1) & 3);   // swizzled fragment chunk

    f32x4 acc[4][4];
#pragma unroll
    for (int i = 0; i < 4; i++)
#pragma unroll
        for (int j = 0; j < 4; j++) acc[i][j] = (f32x4)0.0f;

    for (int kk = 0; kk < K; kk += 32) {
        __syncthreads();
#pragma unroll
        for (int i = 0; i < 2; i++) {
            int c = tid + i * 256;            // 512 chunks of 8 elems (16B)
            int row = c >> 2, j = c & 3;
            int sj = j ^ ((row >> 1) & 3);
            int ldst = row * 32 + sj * 8;
            size_t ga = (size_t)(m0 + row) * K + kk + j * 8;
            size_t gb = (size_t)(n0 + row) * K + kk + j * 8;
            *(s16x8*)&As[0][ldst] = *(const s16x8*)(Ah + ga);
            *(s16x8*)&Bs[0][ldst] = *(const s16x8*)(Bh + gb);
            if constexpr (SPLIT) {
                *(s16x8*)&As[1][ldst] = *(const s16x8*)(Al + ga);
                *(s16x8*)&Bs[1][ldst] = *(const s16x8*)(Bl + gb);
            }
        }
        __syncthreads();

        s16x8 af[4][2], bf[4][2];
#pragma unroll
        for (int mt = 0; mt < 4; mt++) {
            int r = wm + mt * 16 + l16;
            af[mt][0] = *(const s16x8*)&As[0][r * 32 + fsw * 8];
            if constexpr (SPLIT) af[mt][1] = *(const s16x8*)&As[1][r * 32 + fsw * 8];
        }
#pragma unroll
        for (int nt = 0; nt < 4; nt++) {
            int r = wn + nt * 16 + l16;
            bf[nt][0] = *(const s16x8*)&Bs[0][r * 32 + fsw * 8];
            if constexpr (SPLIT) bf[nt][1] = *(const s16x8*)&Bs[1][r * 32 + fsw * 8];
        }
#pragma unroll
        for (int mt = 0; mt < 4; mt++)
#pragma unroll
            for (int nt = 0; nt < 4; nt++) {
                acc[mt][nt] = MFMA(af[mt][0], bf[nt][0], acc[mt][nt]);
                if constexpr (SPLIT) {
                    acc[mt][nt] = MFMA(af[mt][0], bf[nt][1], acc[mt][nt]);
                    acc[mt][nt] = MFMA(af[mt][1], bf[nt][0], acc[mt][nt]);
                }
            }
    }

    // epilogue — C/D layout: col = lane&15, row = quad*4 + reg
#pragma unroll
    for (int mt = 0; mt < 4; mt++)
#pragma unroll
        for (int nt = 0; nt < 4; nt++) {
            if constexpr (OUTMODE == 1) {
                // transposed: 4 consecutive gm per lane -> one 8B store
                int gn = n0 + wn + nt * 16 + l16;
                int gm = m0 + wm + mt * 16 + quad * 4;
                u16x4 pk;
#pragma unroll
                for (int r = 0; r < 4; r++) pk[r] = f2bf(acc[mt][nt][r] + bias[gn]);
                *(u16x4*)&C16h[(size_t)gn * M + gm] = pk;
            } else {
#pragma unroll
                for (int r = 0; r < 4; r++) {
                    int gm = m0 + wm + mt * 16 + quad * 4 + r;
                    int gn = n0 + wn + nt * 16 + l16;
                    float v = acc[mt][nt][r] + bias[gn];
                    if constexpr (OUTMODE == 0) {
                        Cf[(size_t)gm * N + gn] = v;
                    } else {
                        u16 hh = f2bf(v);
                        C16h[(size_t)gm * N + gn] = hh;
                        C16l[(size_t)gm * N + gn] = f2bf(v - bf2f(hh));
                    }
                }
            }
        }
}

// ---------------- flash attention per (b,h) ----------------
// LDS rows: 64 u16 = 8 chunks of 8. Swizzle: chunk' = chunk ^ (row&7)
// -> fragment-read start banks 4*chunk' : 8 distinct x 2 lanes (free).
__global__ __launch_bounds__(256) void k_attn(
    const u16* __restrict__ Qh, const u16* __restrict__ Ql,
    const u16* __restrict__ Kh, const u16* __restrict__ Kl,
    const u16* __restrict__ Vt, u16* __restrict__ ctx) {
    const int bh = blockIdx.y;
    const int b = bh >> 4, h = bh & 15;
    const int q0 = blockIdx.x * 64;
    const int rowBase = b * Ss + q0;
    const int hc = h * 64;

    __shared__ u16 Qs[2][64 * 64];
    __shared__ u16 Ks[2][64 * 64];
    __shared__ u16 Vs[64 * 64];        // [d][t]
    __shared__ u16 Ps[4][16 * 64];     // per-wave [m][t]

    const int tid = threadIdx.x;
    const int wave = tid >> 6, lane = tid & 63;
    const int quad = lane >> 4, l16 = lane & 15;

    // stage Q tile (hi/lo): 64 rows x 64 cols, swizzled
#pragma unroll
    for (int hl = 0; hl < 2; hl++) {
        const u16* g = hl ? Ql : Qh;
#pragma unroll
        for (int i = 0; i < 2; i++) {
            int c = tid + i * 256;             // 512 chunks
            int row = c >> 3, j = c & 7;
            int sj = j ^ (row & 7);
            *(s16x8*)&Qs[hl][row * 64 + sj * 8] =
                *(const s16x8*)(g + (size_t)(rowBase + row) * Ee + hc + j * 8);
        }
    }

    f32x4 o[4];
#pragma unroll
    for (int i = 0; i < 4; i++) o[i] = (f32x4)0.0f;
    float mrow[4] = {-1e30f, -1e30f, -1e30f, -1e30f};
    float lrow[4] = {0.f, 0.f, 0.f, 0.f};

    for (int t0 = 0; t0 < Ss; t0 += 64) {
        const int kRowBase = b * Ss + t0;
        __syncthreads();
#pragma unroll
        for (int hl = 0; hl < 2; hl++) {
            const u16* g = hl ? Kl : Kh;
#pragma unroll
            for (int i = 0; i < 2; i++) {
                int c = tid + i * 256;
                int row = c >> 3, j = c & 7;
                int sj = j ^ (row & 7);
                *(s16x8*)&Ks[hl][row * 64 + sj * 8] =
                    *(const s16x8*)(g + (size_t)(kRowBase + row) * Ee + hc + j * 8);
            }
        }
#pragma unroll
        for (int i = 0; i < 2; i++) {
            int c = tid + i * 256;
            int d = c >> 3, j = c & 7;
            int sj = j ^ (d & 7);
            *(s16x8*)&Vs[d * 64 + sj * 8] =
                *(const s16x8*)(Vt + (size_t)(hc + d) * Mrows + kRowBase + j * 8);
        }
        __syncthreads();

        // S = Q K^T (split: QhKh + QhKl + QlKh), wave owns 16 q-rows
        f32x4 sacc[4];
#pragma unroll
        for (int i = 0; i < 4; i++) sacc[i] = (f32x4)0.0f;
        s16x8 aq[2][2];
#pragma unroll
        for (int kc = 0; kc < 2; kc++) {
            int sj = (kc * 4 + quad) ^ (l16 & 7);
            aq[kc][0] = *(const s16x8*)&Qs[0][(wave * 16 + l16) * 64 + sj * 8];
            aq[kc][1] = *(const s16x8*)&Qs[1][(wave * 16 + l16) * 64 + sj * 8];
        }
#pragma unroll
        for (int nt = 0; nt < 4; nt++) {
#pragma unroll
            for (int kc = 0; kc < 2; kc++) {
                int sj = (kc * 4 + quad) ^ (l16 & 7);
                s16x8 bh16 = *(const s16x8*)&Ks[0][(nt * 16 + l16) * 64 + sj * 8];
                s16x8 bl16 = *(const s16x8*)&Ks[1][(nt * 16 + l16) * 64 + sj * 8];
                sacc[nt] = MFMA(aq[kc][0], bh16, sacc[nt]);
                sacc[nt] = MFMA(aq[kc][0], bl16, sacc[nt]);
                sacc[nt] = MFMA(aq[kc][1], bh16, sacc[nt]);
            }
        }

        // online softmax (rows m = quad*4+r, cols t = nt*16 + l16)
        float sv[4][4];
#pragma unroll
        for (int nt = 0; nt < 4; nt++)
#pragma unroll
            for (int r = 0; r < 4; r++) sv[nt][r] = sacc[nt][r] * 0.125f;

        float mnew[4], alpha[4];
#pragma unroll
        for (int r = 0; r < 4; r++) {
            float t = fmaxf(fmaxf(sv[0][r], sv[1][r]), fmaxf(sv[2][r], sv[3][r]));
#pragma unroll
            for (int off = 1; off < 16; off <<= 1) t = fmaxf(t, __shfl_xor(t, off));
            mnew[r] = fmaxf(mrow[r], t);
            alpha[r] = __expf(mrow[r] - mnew[r]);
            mrow[r] = mnew[r];
        }
#pragma unroll
        for (int nt = 0; nt < 4; nt++)
#pragma unroll
            for (int r = 0; r < 4; r++) sv[nt][r] = __expf(sv[nt][r] - mnew[r]);
#pragma unroll
        for (int r = 0; r < 4; r++) {
            float s = sv[0][r] + sv[1][r] + sv[2][r] + sv[3][r];
#pragma unroll
            for (int off = 1; off < 16; off <<= 1) s += __shfl_xor(s, off);
            lrow[r] = lrow[r] * alpha[r] + s;
        }
        // write P (bf16) to wave-private LDS (swizzled), rescale O
#pragma unroll
        for (int nt = 0; nt < 4; nt++)
#pragma unroll
            for (int r = 0; r < 4; r++) {
                int row = quad * 4 + r;
                int ch = nt * 2 + (l16 >> 3);
                int sj = ch ^ (row & 7);
                Ps[wave][row * 64 + sj * 8 + (l16 & 7)] = f2bf(sv[nt][r]);
                o[nt][r] *= alpha[r];
            }

        // O += P V   (A = P[m][t], B = V[t][d] via Vs[d][t])
#pragma unroll
        for (int kc = 0; kc < 2; kc++) {
            int sj = (kc * 4 + quad) ^ (l16 & 7);
            s16x8 ap = *(const s16x8*)&Ps[wave][l16 * 64 + sj * 8];
#pragma unroll
            for (int nt = 0; nt < 4; nt++) {
                s16x8 bv16 = *(const s16x8*)&Vs[(nt * 16 + l16) * 64 + sj * 8];
                o[nt] = MFMA(ap, bv16, o[nt]);
            }
        }
        __syncthreads();
    }

    // epilogue: ctx[row][h*64+d] = O/l
#pragma unroll
    for (int nt = 0; nt < 4; nt++)
#pragma unroll
        for (int r = 0; r < 4; r++) {
            int gm = rowBase + wave * 16 + quad * 4 + r;
            int gd = hc + nt * 16 + l16;
            ctx[(size_t)gm * Ee + gd] = f2bf(o[nt][r] / lrow[r]);
        }
}

extern "C" void kernel_launch(void* const* d_in, const int* in_sizes, int n_in,
                              void* d_out, int out_size, void* d_ws, size_t ws_size,
                              hipStream_t stream) {
    const float* q  = (const float*)d_in[0];
    const float* kin = (const float*)d_in[1];
    const float* v  = (const float*)d_in[2];
    const float* Wq = (const float*)d_in[3];
    const float* Wk = (const float*)d_in[4];
    const float* Wv = (const float*)d_in[5];
    const float* bq = (const float*)d_in[6];
    const float* bk = (const float*)d_in[7];
    const float* bv = (const float*)d_in[8];
    const float* Wo = (const float*)d_in[9];
    const float* bo = (const float*)d_in[10];

    u16* ws = (u16*)d_ws;
    u16 *qh = ws,          *ql = ws + NE,     *kh = ws + 2 * NE, *kl = ws + 3 * NE;
    u16 *vh = ws + 4 * NE;
    u16 *Qh = ws + 5 * NE, *Ql = ws + 6 * NE, *Kh = ws + 7 * NE, *Kl = ws + 8 * NE;
    u16 *Vt = ws + 9 * NE, *ctx = ws + 10 * NE;
    u16 *WqTh = ws + 11 * NE;
    u16 *WqTl = WqTh + WN, *WkTh = WqTh + 2 * WN, *WkTl = WqTh + 3 * WN;
    u16 *WvTh = WqTh + 4 * WN, *WoTh = WqTh + 5 * WN;

    dim3 b256(256);
    k_split<<<dim3(NE / 256), b256, 0, stream>>>(q,   qh, ql, (int)NE);
    k_split<<<dim3(NE / 256), b256, 0, stream>>>(kin, kh, kl, (int)NE);
    k_split<<<dim3(NE / 256), b256, 0, stream>>>(v,   vh, nullptr, (int)NE);
    k_wT<<<dim3(WN / 256), b256, 0, stream>>>(Wq, WqTh, WqTl, 1);
    k_wT<<<dim3(WN / 256), b256, 0, stream>>>(Wk, WkTh, WkTl, 1);
    k_wT<<<dim3(WN / 256), b256, 0, stream>>>(Wv, WvTh, nullptr, 1);
    k_wT<<<dim3(WN / 256), b256, 0, stream>>>(Wo, WoTh, nullptr, 0);

    dim3 gg(8, 32);   // N/128, M/128
    k_gemm<1, 2><<<gg, b256, 0, stream>>>(qh, ql, WqTh, WqTl, bq, Qh, Ql, nullptr, Mrows, Ee, Ee);
    k_gemm<1, 2><<<gg, b256, 0, stream>>>(kh, kl, WkTh, WkTl, bk, Kh, Kl, nullptr, Mrows, Ee, Ee);
    k_gemm<0, 1><<<gg, b256, 0, stream>>>(vh, nullptr, WvTh, nullptr, bv, Vt, nullptr, nullptr, Mrows, Ee, Ee);

    k_attn<<<dim3(Ss / 64, Bb * Hh), b256, 0, stream>>>(Qh, Ql, Kh, Kl, Vt, ctx);

    k_gemm<0, 0><<<gg, b256, 0, stream>>>(ctx, nullptr, WoTh, nullptr, bo, nullptr, nullptr, (float*)d_out, Mrows, Ee, Ee);
}

// Round 3
// 413.817 us; speedup vs baseline: 1.2874x; 1.2874x over previous
//
#include <hip/hip_runtime.h>
#include <hip/hip_bf16.h>

typedef unsigned short u16;
typedef unsigned int   u32;
typedef __attribute__((ext_vector_type(4))) float f32x4;
typedef __attribute__((ext_vector_type(8))) short s16x8;
typedef __attribute__((ext_vector_type(4))) u16 u16x4;

#define DI __device__ __forceinline__

static constexpr int Bb = 2, Ss = 2048, Hh = 16, Dd = 64, Ee = 1024;
static constexpr int Mrows = Bb * Ss;          // 4096
static constexpr size_t NE = (size_t)Mrows * Ee;   // 4 M elems
static constexpr size_t WN = (size_t)Ee * Ee;      // 1 M elems

DI float bf2f(u16 h) { u32 u = ((u32)h) << 16; return __builtin_bit_cast(float, u); }
DI u16 f2bf(float f) {
    u32 u = __builtin_bit_cast(u32, f);
    u32 r = (u + 0x7FFFu + ((u >> 16) & 1u)) >> 16;
    return (u16)r;
}

#define MFMA(a, b, c) __builtin_amdgcn_mfma_f32_16x16x32_bf16((a), (b), (c), 0, 0, 0)

// async global->LDS, 16B per lane. LDS dest must be uniform-base + lane*16,
// which holds for all call sites below (chunk index == tid-linear).
DI void gld16(const u16* g, u16* l) {
    __builtin_amdgcn_global_load_lds((const __attribute__((address_space(1))) void*)g,
                                     (__attribute__((address_space(3))) void*)l, 16, 0, 0);
}

// ---------------- prep: fp32 -> bf16 hi (+lo) for q,k,v in one dispatch ----------------
__global__ __launch_bounds__(256) void k_split3(
    const float* __restrict__ q, const float* __restrict__ k, const float* __restrict__ v,
    u16* __restrict__ qh, u16* __restrict__ ql,
    u16* __restrict__ kh, u16* __restrict__ kl, u16* __restrict__ vh) {
    int i = blockIdx.x * 256 + threadIdx.x;
    int y = blockIdx.y;
    const float* s = (y == 0) ? q : (y == 1) ? k : v;
    u16* h = (y == 0) ? qh : (y == 1) ? kh : vh;
    u16* l = (y == 0) ? ql : (y == 1) ? kl : nullptr;
    float val = s[i];
    u16 hh = f2bf(val);
    h[i] = hh;
    if (l) l[i] = f2bf(val - bf2f(hh));
}

// ---------------- prep: all 4 weights -> B^T [N][K] bf16 in one dispatch ----------------
__global__ __launch_bounds__(256) void k_wT4(
    const float* __restrict__ Wq, const float* __restrict__ Wk,
    const float* __restrict__ Wv, const float* __restrict__ Wo,
    u16* __restrict__ WqTh, u16* __restrict__ WqTl,
    u16* __restrict__ WkTh, u16* __restrict__ WkTl,
    u16* __restrict__ WvTh, u16* __restrict__ WoTh) {
    int idx = blockIdx.x * 256 + threadIdx.x;   // n*1024 + k
    int y = blockIdx.y;
    int n = idx >> 10, kk = idx & 1023;
    const float* W = (y == 0) ? Wq : (y == 1) ? Wk : (y == 2) ? Wv : Wo;
    float v = (y < 3) ? W[(size_t)(n >> 6) * (Ee * Dd) + (size_t)kk * Dd + (n & 63)]
                      : W[(size_t)kk * Ee + n];
    u16* h = (y == 0) ? WqTh : (y == 1) ? WkTh : (y == 2) ? WvTh : WoTh;
    u16* l = (y == 0) ? WqTl : (y == 1) ? WkTl : nullptr;
    u16 hh = f2bf(v);
    h[idx] = hh;
    if (l) l[idx] = f2bf(v - bf2f(hh));
}

// ---------------- GEMM: C[M][N] = (A[M][K] * B^T[N][K] + bias[n]) * scale ----------------
// LDS linear [128][32] u16 per buffer; staged with global_load_lds width=16.
// Frag reads are conflict-free (start banks 8 distinct spans of 4, 8 lanes each).
// SPLIT=1: hi/lo 3-MFMA. OUTMODE: 0=f32 row-major, 1=bf16 transposed [N][M], 2=bf16 hi/lo.
template <int SPLIT, int OUTMODE>
__global__ __launch_bounds__(256) void k_gemm(
    const u16* __restrict__ Ah, const u16* __restrict__ Al,
    const u16* __restrict__ Bh, const u16* __restrict__ Bl,
    const float* __restrict__ bias,
    u16* __restrict__ C16h, u16* __restrict__ C16l, float* __restrict__ Cf,
    int M, int N, int K, float scale) {
    constexpr int NB = SPLIT ? 2 : 1;
    __shared__ u16 As[NB][128 * 32];
    __shared__ u16 Bs[NB][128 * 32];

    const int tid = threadIdx.x;
    const int wave = tid >> 6, lane = tid & 63;
    const int quad = lane >> 4, l16 = lane & 15;
    const int m0 = blockIdx.y * 128, n0 = blockIdx.x * 128;
    const int wm = (wave >> 1) * 64, wn = (wave & 1) * 64;

    f32x4 acc[4][4];
#pragma unroll
    for (int i = 0; i < 4; i++)
#pragma unroll
        for (int j = 0; j < 4; j++) acc[i][j] = (f32x4)0.0f;

    for (int kk = 0; kk < K; kk += 32) {
        __syncthreads();
#pragma unroll
        for (int i = 0; i < 2; i++) {
            int c = tid + i * 256;            // 512 chunks of 8 elems (16B), lane-linear
            int row = c >> 2, j = c & 3;
            size_t ga = (size_t)(m0 + row) * K + kk + j * 8;
            size_t gb = (size_t)(n0 + row) * K + kk + j * 8;
            gld16(Ah + ga, &As[0][c * 8]);
            gld16(Bh + gb, &Bs[0][c * 8]);
            if constexpr (SPLIT) {
                gld16(Al + ga, &As[1][c * 8]);
                gld16(Bl + gb, &Bs[1][c * 8]);
            }
        }
        __syncthreads();

        s16x8 af[4][2], bf[4][2];
#pragma unroll
        for (int mt = 0; mt < 4; mt++) {
            int r = wm + mt * 16 + l16;
            af[mt][0] = *(const s16x8*)&As[0][r * 32 + quad * 8];
            if constexpr (SPLIT) af[mt][1] = *(const s16x8*)&As[1][r * 32 + quad * 8];
        }
#pragma unroll
        for (int nt = 0; nt < 4; nt++) {
            int r = wn + nt * 16 + l16;
            bf[nt][0] = *(const s16x8*)&Bs[0][r * 32 + quad * 8];
            if constexpr (SPLIT) bf[nt][1] = *(const s16x8*)&Bs[1][r * 32 + quad * 8];
        }
#pragma unroll
        for (int mt = 0; mt < 4; mt++)
#pragma unroll
            for (int nt = 0; nt < 4; nt++) {
                acc[mt][nt] = MFMA(af[mt][0], bf[nt][0], acc[mt][nt]);
                if constexpr (SPLIT) {
                    acc[mt][nt] = MFMA(af[mt][0], bf[nt][1], acc[mt][nt]);
                    acc[mt][nt] = MFMA(af[mt][1], bf[nt][0], acc[mt][nt]);
                }
            }
    }

    // epilogue — C/D layout: col = lane&15, row = quad*4 + reg
#pragma unroll
    for (int mt = 0; mt < 4; mt++)
#pragma unroll
        for (int nt = 0; nt < 4; nt++) {
            if constexpr (OUTMODE == 1) {
                int gn = n0 + wn + nt * 16 + l16;
                int gm = m0 + wm + mt * 16 + quad * 4;
                u16x4 pk;
#pragma unroll
                for (int r = 0; r < 4; r++) pk[r] = f2bf((acc[mt][nt][r] + bias[gn]) * scale);
                *(u16x4*)&C16h[(size_t)gn * M + gm] = pk;
            } else {
#pragma unroll
                for (int r = 0; r < 4; r++) {
                    int gm = m0 + wm + mt * 16 + quad * 4 + r;
                    int gn = n0 + wn + nt * 16 + l16;
                    float v = (acc[mt][nt][r] + bias[gn]) * scale;
                    if constexpr (OUTMODE == 0) {
                        Cf[(size_t)gm * N + gn] = v;
                    } else {
                        u16 hh = f2bf(v);
                        C16h[(size_t)gm * N + gn] = hh;
                        C16l[(size_t)gm * N + gn] = f2bf(v - bf2f(hh));
                    }
                }
            }
        }
}

// ---------------- flash attention, S^T formulation ----------------
// Block: 128 q-rows, 4 waves; each wave owns 32 q-cols (2 n-tiles), all 64 t per iter.
// S^T[t][q] = K[t][:]·Q[q][:]  (A=K from LDS, B=Q loop-invariant in registers).
// C-layout: each lane owns entire q-columns -> softmax needs only 2 shuffles per reduce.
// O^T[d][q] += V^T[d][t]·P^T[t][q] (A=Vs[d][t], B=P from wave-private LDS [q][t]).
// Q pre-scaled by 1/8 at projection.
__global__ __launch_bounds__(256, 2) void k_attn(
    const u16* __restrict__ Qh, const u16* __restrict__ Ql,
    const u16* __restrict__ Kh, const u16* __restrict__ Kl,
    const u16* __restrict__ Vt, u16* __restrict__ ctx) {
    const int bh = blockIdx.y;
    const int b = bh >> 4, h = bh & 15;
    const int q0 = blockIdx.x * 128;
    const int rowBase = b * Ss + q0;
    const int hc = h * 64;

    __shared__ u16 Ks[2][64 * 64];     // [t][d], xor-swizzled chunks
    __shared__ u16 Vs[64 * 64];        // [d][t], xor-swizzled chunks
    __shared__ u16 Ps[4][32 * 72];     // per-wave [qloc][t], padded row 72

    const int tid = threadIdx.x;
    const int wave = tid >> 6, lane = tid & 63;
    const int quad = lane >> 4, l16 = lane & 15;

    // loop-invariant Q B-frags: bq[nt2][kc][hl], lane n=q reads k-contiguous 16B
    s16x8 bq[2][2][2];
#pragma unroll
    for (int nt2 = 0; nt2 < 2; nt2++) {
        int row = rowBase + wave * 32 + nt2 * 16 + l16;
#pragma unroll
        for (int kc = 0; kc < 2; kc++) {
            bq[nt2][kc][0] = *(const s16x8*)(Qh + (size_t)row * Ee + hc + kc * 32 + quad * 8);
            bq[nt2][kc][1] = *(const s16x8*)(Ql + (size_t)row * Ee + hc + kc * 32 + quad * 8);
        }
    }

    f32x4 o[2][4];
#pragma unroll
    for (int n2 = 0; n2 < 2; n2++)
#pragma unroll
        for (int mt = 0; mt < 4; mt++) o[n2][mt] = (f32x4)0.0f;
    float m_[2] = {-1e30f, -1e30f};
    float l_[2] = {0.f, 0.f};

    for (int t0 = 0; t0 < Ss; t0 += 64) {
        const int kRowBase = b * Ss + t0;
        __syncthreads();
        // stage K hi/lo + V (VGPR path, xor-swizzled: chunk' = chunk ^ (row&7))
#pragma unroll
        for (int hl = 0; hl < 2; hl++) {
            const u16* g = hl ? Kl : Kh;
#pragma unroll
            for (int i = 0; i < 2; i++) {
                int c = tid + i * 256;
                int row = c >> 3, j = c & 7;
                int sj = j ^ (row & 7);
                *(s16x8*)&Ks[hl][row * 64 + sj * 8] =
                    *(const s16x8*)(g + (size_t)(kRowBase + row) * Ee + hc + j * 8);
            }
        }
#pragma unroll
        for (int i = 0; i < 2; i++) {
            int c = tid + i * 256;
            int d = c >> 3, j = c & 7;
            int sj = j ^ (d & 7);
            *(s16x8*)&Vs[d * 64 + sj * 8] =
                *(const s16x8*)(Vt + (size_t)(hc + d) * Mrows + kRowBase + j * 8);
        }
        __syncthreads();

        // S^T = K·Q^T (split: KhQh + KhQl + KlQh); st[nt2][mt], t = mt*16+quad*4+r, q-col = l16
        f32x4 st[2][4];
#pragma unroll
        for (int n2 = 0; n2 < 2; n2++)
#pragma unroll
            for (int mt = 0; mt < 4; mt++) st[n2][mt] = (f32x4)0.0f;
#pragma unroll
        for (int mt = 0; mt < 4; mt++) {
            int tr = mt * 16 + l16;
            s16x8 ak[2][2];
#pragma unroll
            for (int kc = 0; kc < 2; kc++) {
                int sj = (kc * 4 + quad) ^ (l16 & 7);
                ak[kc][0] = *(const s16x8*)&Ks[0][tr * 64 + sj * 8];
                ak[kc][1] = *(const s16x8*)&Ks[1][tr * 64 + sj * 8];
            }
#pragma unroll
            for (int n2 = 0; n2 < 2; n2++)
#pragma unroll
                for (int kc = 0; kc < 2; kc++) {
                    st[n2][mt] = MFMA(ak[kc][0], bq[n2][kc][0], st[n2][mt]);
                    st[n2][mt] = MFMA(ak[kc][0], bq[n2][kc][1], st[n2][mt]);
                    st[n2][mt] = MFMA(ak[kc][1], bq[n2][kc][0], st[n2][mt]);
                }
        }

        // online softmax per q-column (2 per lane), P -> wave-private LDS
#pragma unroll
        for (int n2 = 0; n2 < 2; n2++) {
            float t01 = fmaxf(fmaxf(st[n2][0][0], st[n2][0][1]), fmaxf(st[n2][0][2], st[n2][0][3]));
            float t23 = fmaxf(fmaxf(st[n2][1][0], st[n2][1][1]), fmaxf(st[n2][1][2], st[n2][1][3]));
            float t45 = fmaxf(fmaxf(st[n2][2][0], st[n2][2][1]), fmaxf(st[n2][2][2], st[n2][2][3]));
            float t67 = fmaxf(fmaxf(st[n2][3][0], st[n2][3][1]), fmaxf(st[n2][3][2], st[n2][3][3]));
            float tmax = fmaxf(fmaxf(t01, t23), fmaxf(t45, t67));
            tmax = fmaxf(tmax, __shfl_xor(tmax, 16));
            tmax = fmaxf(tmax, __shfl_xor(tmax, 32));
            float mnew = fmaxf(m_[n2], tmax);
            float al = __expf(m_[n2] - mnew);
            m_[n2] = mnew;
            float psum = 0.f;
            u16x4 pk[4];
#pragma unroll
            for (int mt = 0; mt < 4; mt++) {
#pragma unroll
                for (int r = 0; r < 4; r++) {
                    float p = __expf(st[n2][mt][r] - mnew);
                    psum += p;
                    pk[mt][r] = f2bf(p);
                }
            }
            psum += __shfl_xor(psum, 16);
            psum += __shfl_xor(psum, 32);
            l_[n2] = l_[n2] * al + psum;
            int qloc = n2 * 16 + l16;
#pragma unroll
            for (int mt = 0; mt < 4; mt++)
                *(u16x4*)&Ps[wave][qloc * 72 + mt * 16 + quad * 4] = pk[mt];
#pragma unroll
            for (int mt = 0; mt < 4; mt++) o[n2][mt] *= al;
        }

        // O^T += V^T P^T  (A = Vs[d][t], B = Ps[q][t])
#pragma unroll
        for (int kc = 0; kc < 2; kc++) {
            s16x8 bp[2];
#pragma unroll
            for (int n2 = 0; n2 < 2; n2++)
                bp[n2] = *(const s16x8*)&Ps[wave][(n2 * 16 + l16) * 72 + kc * 32 + quad * 8];
#pragma unroll
            for (int mt = 0; mt < 4; mt++) {
                int sj = (kc * 4 + quad) ^ (l16 & 7);
                s16x8 av = *(const s16x8*)&Vs[(mt * 16 + l16) * 64 + sj * 8];
#pragma unroll
                for (int n2 = 0; n2 < 2; n2++) o[n2][mt] = MFMA(av, bp[n2], o[n2][mt]);
            }
        }
    }

    // epilogue: ctx[q][hc + d], d = mt*16 + quad*4 + r  -> 8B packed stores
#pragma unroll
    for (int n2 = 0; n2 < 2; n2++) {
        float inv = 1.0f / l_[n2];
        int gm = rowBase + wave * 32 + n2 * 16 + l16;
#pragma unroll
        for (int mt = 0; mt < 4; mt++) {
            u16x4 pk;
#pragma unroll
            for (int r = 0; r < 4; r++) pk[r] = f2bf(o[n2][mt][r] * inv);
            *(u16x4*)&ctx[(size_t)gm * Ee + hc + mt * 16 + quad * 4] = pk;
        }
    }
}

extern "C" void kernel_launch(void* const* d_in, const int* in_sizes, int n_in,
                              void* d_out, int out_size, void* d_ws, size_t ws_size,
                              hipStream_t stream) {
    const float* q  = (const float*)d_in[0];
    const float* kin = (const float*)d_in[1];
    const float* v  = (const float*)d_in[2];
    const float* Wq = (const float*)d_in[3];
    const float* Wk = (const float*)d_in[4];
    const float* Wv = (const float*)d_in[5];
    const float* bq = (const float*)d_in[6];
    const float* bk = (const float*)d_in[7];
    const float* bv = (const float*)d_in[8];
    const float* Wo = (const float*)d_in[9];
    const float* bo = (const float*)d_in[10];

    u16* ws = (u16*)d_ws;
    u16 *qh = ws,          *ql = ws + NE,     *kh = ws + 2 * NE, *kl = ws + 3 * NE;
    u16 *vh = ws + 4 * NE;
    u16 *Qh = ws + 5 * NE, *Ql = ws + 6 * NE, *Kh = ws + 7 * NE, *Kl = ws + 8 * NE;
    u16 *Vt = ws + 9 * NE, *ctx = ws + 10 * NE;
    u16 *WqTh = ws + 11 * NE;
    u16 *WqTl = WqTh + WN, *WkTh = WqTh + 2 * WN, *WkTl = WqTh + 3 * WN;
    u16 *WvTh = WqTh + 4 * WN, *WoTh = WqTh + 5 * WN;

    dim3 b256(256);
    k_split3<<<dim3(NE / 256, 3), b256, 0, stream>>>(q, kin, v, qh, ql, kh, kl, vh);
    k_wT4<<<dim3(WN / 256, 4), b256, 0, stream>>>(Wq, Wk, Wv, Wo,
                                                  WqTh, WqTl, WkTh, WkTl, WvTh, WoTh);

    dim3 gg(8, 32);   // N/128, M/128
    // Q projection pre-scaled by 1/8 (softmax scale folded in)
    k_gemm<1, 2><<<gg, b256, 0, stream>>>(qh, ql, WqTh, WqTl, bq, Qh, Ql, nullptr,
                                          Mrows, Ee, Ee, 0.125f);
    k_gemm<1, 2><<<gg, b256, 0, stream>>>(kh, kl, WkTh, WkTl, bk, Kh, Kl, nullptr,
                                          Mrows, Ee, Ee, 1.0f);
    k_gemm<0, 1><<<gg, b256, 0, stream>>>(vh, nullptr, WvTh, nullptr, bv, Vt, nullptr, nullptr,
                                          Mrows, Ee, Ee, 1.0f);

    k_attn<<<dim3(Ss / 128, Bb * Hh), b256, 0, stream>>>(Qh, Ql, Kh, Kl, Vt, ctx);

    k_gemm<0, 0><<<gg, b256, 0, stream>>>(ctx, nullptr, WoTh, nullptr, bo, nullptr, nullptr,
                                          (float*)d_out, Mrows, Ee, Ee, 1.0f);
}

// Round 6
// 327.813 us; speedup vs baseline: 1.6252x; 1.2624x over previous
//
#include <hip/hip_runtime.h>
#include <hip/hip_bf16.h>

typedef unsigned short u16;
typedef unsigned int   u32;
typedef _Float16 f16;
typedef __attribute__((ext_vector_type(4))) float f32x4;
typedef __attribute__((ext_vector_type(8))) short s16x8;
typedef __attribute__((ext_vector_type(8))) f16 f16x8;
typedef __attribute__((ext_vector_type(2))) __fp16 fp16x2;
typedef __attribute__((ext_vector_type(4))) u16 u16x4;
typedef __attribute__((ext_vector_type(2))) u32 u32x2;

#define DI __device__ __forceinline__

static constexpr int Bb = 2, Ss = 2048, Hh = 16, Dd = 64, Ee = 1024;
static constexpr int Mrows = Bb * Ss;              // 4096
static constexpr size_t NE = (size_t)Mrows * Ee;   // 4 M elems
static constexpr size_t WN = (size_t)Ee * Ee;      // 1 M elems
static constexpr float QSCALE = 0.125f * 1.44269504088896f;  // 1/8 * log2(e)

DI float bf2f(u16 h) { u32 u = ((u32)h) << 16; return __builtin_bit_cast(float, u); }
DI u16 f2bf(float f) {
    u32 u = __builtin_bit_cast(u32, f);
    u32 r = (u + 0x7FFFu + ((u >> 16) & 1u)) >> 16;
    return (u16)r;
}
DI u16 f2h(float f) { f16 h = (f16)f; return __builtin_bit_cast(u16, h); }
DI u32 pkrtz(float a, float b) {
    fp16x2 r = __builtin_amdgcn_cvt_pkrtz(a, b);
    return __builtin_bit_cast(u32, r);
}
DI float ex2(float x) { return __builtin_amdgcn_exp2f(x); }

#define MFMA_BF(a, b, c) __builtin_amdgcn_mfma_f32_16x16x32_bf16((a), (b), (c), 0, 0, 0)
#define MFMA_F16(a, b, c) __builtin_amdgcn_mfma_f32_16x16x32_f16( \
    __builtin_bit_cast(f16x8, (a)), __builtin_bit_cast(f16x8, (b)), (c), 0, 0, 0)

// async global->LDS, 16B per lane (LDS dest must be lane-linear)
DI void gld16(const u16* g, u16* l) {
    __builtin_amdgcn_global_load_lds((const __attribute__((address_space(1))) void*)g,
                                     (__attribute__((address_space(3))) void*)l, 16, 0, 0);
}

// ---------------- prep: q,k -> bf16 hi/lo; v -> fp16 ----------------
__global__ __launch_bounds__(256) void k_split3(
    const float* __restrict__ q, const float* __restrict__ k, const float* __restrict__ v,
    u16* __restrict__ qh, u16* __restrict__ ql,
    u16* __restrict__ kh, u16* __restrict__ kl, u16* __restrict__ vh) {
    int i = blockIdx.x * 256 + threadIdx.x;
    int y = blockIdx.y;
    if (y == 2) { vh[i] = f2h(v[i]); return; }
    const float* s = y ? k : q;
    u16* h = y ? kh : qh;
    u16* l = y ? kl : ql;
    float val = s[i];
    u16 hh = f2bf(val);
    h[i] = hh;
    l[i] = f2bf(val - bf2f(hh));
}

// ---------------- prep: weights -> B^T [N][K] via LDS-tiled transpose ----------------
// y=0: Wq -> bf16 hi/lo; y=1: Wk -> bf16 hi/lo; y=2: Wv -> fp16; y=3: Wo -> fp16.
__global__ __launch_bounds__(256) void k_wprep(
    const float* __restrict__ Wq, const float* __restrict__ Wk,
    const float* __restrict__ Wv, const float* __restrict__ Wo,
    u16* __restrict__ WqTh, u16* __restrict__ WqTl,
    u16* __restrict__ WkTh, u16* __restrict__ WkTl,
    u16* __restrict__ WvT, u16* __restrict__ WoT) {
    __shared__ float Ts[64 * 65];
    const int y = blockIdx.y;
    const int ti = blockIdx.x >> 4, tj = blockIdx.x & 15;   // n-tile, k-tile
    const float* W = (y == 0) ? Wq : (y == 1) ? Wk : (y == 2) ? Wv : Wo;
    const int t = threadIdx.x;
    const int col = t & 63, rb = (t >> 6) * 16;
#pragma unroll
    for (int rr = 0; rr < 16; rr++) {
        int row = rb + rr;   // k-local
        float v = (y < 3) ? W[(size_t)ti * 65536 + (size_t)(tj * 64 + row) * 64 + col]
                          : W[(size_t)(tj * 64 + row) * Ee + ti * 64 + col];
        Ts[row * 65 + col] = v;
    }
    __syncthreads();
#pragma unroll
    for (int rr = 0; rr < 16; rr++) {
        int orow = rb + rr;  // n-local
        int ocol = col;      // k-local (coalesced)
        float v = Ts[ocol * 65 + orow];
        size_t oidx = (size_t)(ti * 64 + orow) * Ee + tj * 64 + ocol;
        if (y == 0) {
            u16 hh = f2bf(v); WqTh[oidx] = hh; WqTl[oidx] = f2bf(v - bf2f(hh));
        } else if (y == 1) {
            u16 hh = f2bf(v); WkTh[oidx] = hh; WkTl[oidx] = f2bf(v - bf2f(hh));
        } else if (y == 2) {
            WvT[oidx] = f2h(v);
        } else {
            WoT[oidx] = f2h(v);
        }
    }
}

// ---------------- GEMM body: C = (A[M][K] * B^T[N][K] + bias) * scale ----------------
// SPLIT=1: bf16 hi/lo 3-MFMA. F16=1: fp16 MFMA.
// OUTMODE: 0 = f32 row-major, 1 = fp16 transposed [N][M], 2 = bf16 hi/lo row-major.
template <int SPLIT, int F16, int OUTMODE>
DI void gemm_body(const u16* __restrict__ Ah, const u16* __restrict__ Al,
                  const u16* __restrict__ Bh, const u16* __restrict__ Bl,
                  const float* __restrict__ bias,
                  u16* __restrict__ C16h, u16* __restrict__ C16l, float* __restrict__ Cf,
                  float scale, u16* As0, u16* As1, u16* Bs0, u16* Bs1) {
    constexpr int M = Mrows, N = Ee, K = Ee;
    const int tid = threadIdx.x;
    const int wave = tid >> 6, lane = tid & 63;
    const int quad = lane >> 4, l16 = lane & 15;
    const int m0 = blockIdx.y * 128, n0 = blockIdx.x * 128;
    const int wm = (wave >> 1) * 64, wn = (wave & 1) * 64;

    f32x4 acc[4][4];
#pragma unroll
    for (int i = 0; i < 4; i++)
#pragma unroll
        for (int j = 0; j < 4; j++) acc[i][j] = (f32x4)0.0f;

    for (int kk = 0; kk < K; kk += 32) {
        __syncthreads();
#pragma unroll
        for (int i = 0; i < 2; i++) {
            int c = tid + i * 256;            // 512 chunks of 16B, lane-linear
            int row = c >> 2, j = c & 3;
            size_t ga = (size_t)(m0 + row) * K + kk + j * 8;
            size_t gb = (size_t)(n0 + row) * K + kk + j * 8;
            gld16(Ah + ga, As0 + c * 8);
            gld16(Bh + gb, Bs0 + c * 8);
            if constexpr (SPLIT) {
                gld16(Al + ga, As1 + c * 8);
                gld16(Bl + gb, Bs1 + c * 8);
            }
        }
        __syncthreads();

        s16x8 af[4][2], bf[4][2];
#pragma unroll
        for (int mt = 0; mt < 4; mt++) {
            int r = wm + mt * 16 + l16;
            af[mt][0] = *(const s16x8*)&As0[r * 32 + quad * 8];
            if constexpr (SPLIT) af[mt][1] = *(const s16x8*)&As1[r * 32 + quad * 8];
        }
#pragma unroll
        for (int nt = 0; nt < 4; nt++) {
            int r = wn + nt * 16 + l16;
            bf[nt][0] = *(const s16x8*)&Bs0[r * 32 + quad * 8];
            if constexpr (SPLIT) bf[nt][1] = *(const s16x8*)&Bs1[r * 32 + quad * 8];
        }
#pragma unroll
        for (int mt = 0; mt < 4; mt++)
#pragma unroll
            for (int nt = 0; nt < 4; nt++) {
                if constexpr (F16) {
                    acc[mt][nt] = MFMA_F16(af[mt][0], bf[nt][0], acc[mt][nt]);
                } else {
                    acc[mt][nt] = MFMA_BF(af[mt][0], bf[nt][0], acc[mt][nt]);
                    if constexpr (SPLIT) {
                        acc[mt][nt] = MFMA_BF(af[mt][0], bf[nt][1], acc[mt][nt]);
                        acc[mt][nt] = MFMA_BF(af[mt][1], bf[nt][0], acc[mt][nt]);
                    }
                }
            }
    }

    // epilogue — C/D layout: col = lane&15, row = quad*4 + reg
#pragma unroll
    for (int mt = 0; mt < 4; mt++)
#pragma unroll
        for (int nt = 0; nt < 4; nt++) {
            int gn = n0 + wn + nt * 16 + l16;
            float bs = bias[gn];
            if constexpr (OUTMODE == 1) {
                int gm = m0 + wm + mt * 16 + quad * 4;
                u16x4 pk;
#pragma unroll
                for (int r = 0; r < 4; r++) pk[r] = f2h((acc[mt][nt][r] + bs) * scale);
                *(u16x4*)&C16h[(size_t)gn * M + gm] = pk;
            } else {
#pragma unroll
                for (int r = 0; r < 4; r++) {
                    int gm = m0 + wm + mt * 16 + quad * 4 + r;
                    float v = (acc[mt][nt][r] + bs) * scale;
                    if constexpr (OUTMODE == 0) {
                        Cf[(size_t)gm * N + gn] = v;
                    } else {
                        u16 hh = f2bf(v);
                        C16h[(size_t)gm * N + gn] = hh;
                        C16l[(size_t)gm * N + gn] = f2bf(v - bf2f(hh));
                    }
                }
            }
        }
}

// ---------------- fused Q/K/V projections (grid.z selects) ----------------
__global__ __launch_bounds__(256) void k_qkv(
    const u16* __restrict__ qh, const u16* __restrict__ ql,
    const u16* __restrict__ kh, const u16* __restrict__ kl,
    const u16* __restrict__ vh,
    const u16* __restrict__ WqTh, const u16* __restrict__ WqTl,
    const u16* __restrict__ WkTh, const u16* __restrict__ WkTl,
    const u16* __restrict__ WvT,
    const float* __restrict__ bq, const float* __restrict__ bk, const float* __restrict__ bv,
    u16* __restrict__ Qh, u16* __restrict__ Ql2,
    u16* __restrict__ Kh, u16* __restrict__ Kl2, u16* __restrict__ Vt) {
    __shared__ u16 As[2][128 * 32];
    __shared__ u16 Bs[2][128 * 32];
    int z = blockIdx.z;
    if (z == 0)
        gemm_body<1, 0, 2>(qh, ql, WqTh, WqTl, bq, Qh, Ql2, nullptr, QSCALE,
                           As[0], As[1], Bs[0], Bs[1]);
    else if (z == 1)
        gemm_body<1, 0, 2>(kh, kl, WkTh, WkTl, bk, Kh, Kl2, nullptr, 1.0f,
                           As[0], As[1], Bs[0], Bs[1]);
    else
        gemm_body<0, 1, 1>(vh, nullptr, WvT, nullptr, bv, Vt, nullptr, nullptr, 1.0f,
                           As[0], As[1], Bs[0], Bs[1]);
}

// ---------------- output projection: ctx(fp16) @ WoT(fp16) + bo -> f32 ----------------
__global__ __launch_bounds__(256) void k_out(
    const u16* __restrict__ ctx, const u16* __restrict__ WoT,
    const float* __restrict__ bo, float* __restrict__ out) {
    __shared__ u16 As[128 * 32];
    __shared__ u16 Bs[128 * 32];
    gemm_body<0, 1, 0>(ctx, nullptr, WoT, nullptr, bo, nullptr, nullptr, out, 1.0f,
                       As, nullptr, Bs, nullptr);
}

// ---------------- flash attention, S^T formulation, 64-row q-tiles ----------------
// Score path: bf16 hi/lo split (QhKh + QhKl + QlKh) — required precision (round-5 lesson:
// fp16 scores give absmax ~432 via softmax near-tie flips; split-bf16 gives ~32).
// V/P/ctx path: fp16. Q pre-scaled by log2e/8; exp2-domain softmax.
// S^T[t][q] = K[t][:]·Q[q][:] (A=K LDS, B=Q regs); O^T[d][q] += V^T[d][t]·P^T[t][q].
__global__ __launch_bounds__(256, 4) void k_attn(
    const u16* __restrict__ Qh, const u16* __restrict__ Ql,
    const u16* __restrict__ Kh, const u16* __restrict__ Kl,
    const u16* __restrict__ Vt, u16* __restrict__ ctx) {
    const int bh = blockIdx.y;
    const int b = bh >> 4, h = bh & 15;
    const int q0 = blockIdx.x * 64;
    const int rowBase = b * Ss + q0;
    const int hc = h * 64;

    __shared__ u16 Ks[2][64 * 64];     // [t][d] bf16 hi/lo, xor-swizzled chunks
    __shared__ u16 Vs[64 * 64];        // [d][t] fp16, xor-swizzled chunks
    __shared__ u16 Ps[4][16 * 72];     // per-wave [qloc][t] fp16, padded row 72

    const int tid = threadIdx.x;
    const int wave = tid >> 6, lane = tid & 63;
    const int quad = lane >> 4, l16 = lane & 15;

    // loop-invariant Q B-frags bq[kc][hl] (lane n = q, k-contiguous 16B)
    s16x8 bq[2][2];
    {
        int row = rowBase + wave * 16 + l16;
#pragma unroll
        for (int kc = 0; kc < 2; kc++) {
            bq[kc][0] = *(const s16x8*)(Qh + (size_t)row * Ee + hc + kc * 32 + quad * 8);
            bq[kc][1] = *(const s16x8*)(Ql + (size_t)row * Ee + hc + kc * 32 + quad * 8);
        }
    }

    f32x4 o[4];
#pragma unroll
    for (int mt = 0; mt < 4; mt++) o[mt] = (f32x4)0.0f;
    float m_ = -1e30f, l_ = 0.f;

    for (int t0 = 0; t0 < Ss; t0 += 64) {
        const int kRowBase = b * Ss + t0;
        __syncthreads();
#pragma unroll
        for (int i = 0; i < 2; i++) {
            int c = tid + i * 256;
            int row = c >> 3, j = c & 7;
            int sj = j ^ (row & 7);
            *(s16x8*)&Ks[0][row * 64 + sj * 8] =
                *(const s16x8*)(Kh + (size_t)(kRowBase + row) * Ee + hc + j * 8);
            *(s16x8*)&Ks[1][row * 64 + sj * 8] =
                *(const s16x8*)(Kl + (size_t)(kRowBase + row) * Ee + hc + j * 8);
            *(s16x8*)&Vs[row * 64 + sj * 8] =
                *(const s16x8*)(Vt + (size_t)(hc + row) * Mrows + kRowBase + j * 8);
        }
        __syncthreads();

        // S^T = K·Q^T (split); st[mt], t = mt*16 + quad*4 + r, q-col = l16
        f32x4 st[4];
#pragma unroll
        for (int mt = 0; mt < 4; mt++) st[mt] = (f32x4)0.0f;
#pragma unroll
        for (int mt = 0; mt < 4; mt++) {
            int tr = mt * 16 + l16;
#pragma unroll
            for (int kc = 0; kc < 2; kc++) {
                int sj = (kc * 4 + quad) ^ (l16 & 7);
                s16x8 akh = *(const s16x8*)&Ks[0][tr * 64 + sj * 8];
                s16x8 akl = *(const s16x8*)&Ks[1][tr * 64 + sj * 8];
                st[mt] = MFMA_BF(akh, bq[kc][0], st[mt]);
                st[mt] = MFMA_BF(akh, bq[kc][1], st[mt]);
                st[mt] = MFMA_BF(akl, bq[kc][0], st[mt]);
            }
        }

        // online softmax per q-column (1 per lane), exp2 domain
        float t01 = fmaxf(fmaxf(st[0][0], st[0][1]), fmaxf(st[0][2], st[0][3]));
        float t23 = fmaxf(fmaxf(st[1][0], st[1][1]), fmaxf(st[1][2], st[1][3]));
        float t45 = fmaxf(fmaxf(st[2][0], st[2][1]), fmaxf(st[2][2], st[2][3]));
        float t67 = fmaxf(fmaxf(st[3][0], st[3][1]), fmaxf(st[3][2], st[3][3]));
        float tmax = fmaxf(fmaxf(t01, t23), fmaxf(t45, t67));
        tmax = fmaxf(tmax, __shfl_xor(tmax, 16));
        tmax = fmaxf(tmax, __shfl_xor(tmax, 32));
        float mnew = fmaxf(m_, tmax);
        float al = ex2(m_ - mnew);
        m_ = mnew;
        float psum = 0.f;
#pragma unroll
        for (int mt = 0; mt < 4; mt++) {
            float p0 = ex2(st[mt][0] - mnew);
            float p1 = ex2(st[mt][1] - mnew);
            float p2 = ex2(st[mt][2] - mnew);
            float p3 = ex2(st[mt][3] - mnew);
            psum += (p0 + p1) + (p2 + p3);
            u32x2 pk;
            pk[0] = pkrtz(p0, p1);
            pk[1] = pkrtz(p2, p3);
            *(u32x2*)&Ps[wave][l16 * 72 + mt * 16 + quad * 4] = pk;
        }
        psum += __shfl_xor(psum, 16);
        psum += __shfl_xor(psum, 32);
        l_ = l_ * al + psum;
#pragma unroll
        for (int mt = 0; mt < 4; mt++) o[mt] *= al;

        // O^T += V^T P^T  (A = Vs[d][t], B = Ps[q][t])
#pragma unroll
        for (int kc = 0; kc < 2; kc++) {
            s16x8 bp = *(const s16x8*)&Ps[wave][l16 * 72 + kc * 32 + quad * 8];
#pragma unroll
            for (int mt = 0; mt < 4; mt++) {
                int sj = (kc * 4 + quad) ^ (l16 & 7);
                s16x8 av = *(const s16x8*)&Vs[(mt * 16 + l16) * 64 + sj * 8];
                o[mt] = MFMA_F16(av, bp, o[mt]);
            }
        }
    }

    // epilogue: ctx[q][hc+d] fp16, d = mt*16 + quad*4 + r  -> 8B packed stores
    float inv = 1.0f / l_;
    int gm = rowBase + wave * 16 + l16;
#pragma unroll
    for (int mt = 0; mt < 4; mt++) {
        u32x2 pk;
        pk[0] = pkrtz(o[mt][0] * inv, o[mt][1] * inv);
        pk[1] = pkrtz(o[mt][2] * inv, o[mt][3] * inv);
        *(u32x2*)&ctx[(size_t)gm * Ee + hc + mt * 16 + quad * 4] = pk;
    }
}

extern "C" void kernel_launch(void* const* d_in, const int* in_sizes, int n_in,
                              void* d_out, int out_size, void* d_ws, size_t ws_size,
                              hipStream_t stream) {
    const float* q   = (const float*)d_in[0];
    const float* kin = (const float*)d_in[1];
    const float* v   = (const float*)d_in[2];
    const float* Wq  = (const float*)d_in[3];
    const float* Wk  = (const float*)d_in[4];
    const float* Wv  = (const float*)d_in[5];
    const float* bq  = (const float*)d_in[6];
    const float* bk  = (const float*)d_in[7];
    const float* bv  = (const float*)d_in[8];
    const float* Wo  = (const float*)d_in[9];
    const float* bo  = (const float*)d_in[10];

    u16* ws = (u16*)d_ws;
    u16 *qh = ws,          *ql = ws + NE,     *kh = ws + 2 * NE, *kl = ws + 3 * NE;
    u16 *vh = ws + 4 * NE;
    u16 *Qh = ws + 5 * NE, *Ql = ws + 6 * NE, *Kh = ws + 7 * NE, *Kl = ws + 8 * NE;
    u16 *Vt = ws + 9 * NE, *ctx = ws + 10 * NE;
    u16 *WqTh = ws + 11 * NE;
    u16 *WqTl = WqTh + WN, *WkTh = WqTh + 2 * WN, *WkTl = WqTh + 3 * WN;
    u16 *WvT = WqTh + 4 * WN, *WoT = WqTh + 5 * WN;

    dim3 b256(256);
    k_split3<<<dim3(NE / 256, 3), b256, 0, stream>>>(q, kin, v, qh, ql, kh, kl, vh);
    k_wprep<<<dim3(256, 4), b256, 0, stream>>>(Wq, Wk, Wv, Wo,
                                               WqTh, WqTl, WkTh, WkTl, WvT, WoT);

    k_qkv<<<dim3(8, 32, 3), b256, 0, stream>>>(qh, ql, kh, kl, vh,
                                               WqTh, WqTl, WkTh, WkTl, WvT,
                                               bq, bk, bv, Qh, Ql, Kh, Kl, Vt);

    k_attn<<<dim3(Ss / 64, Bb * Hh), b256, 0, stream>>>(Qh, Ql, Kh, Kl, Vt, ctx);

    k_out<<<dim3(8, 32), b256, 0, stream>>>(ctx, WoT, bo, (float*)d_out);
}

// Round 7
// 324.945 us; speedup vs baseline: 1.6395x; 1.0088x over previous
//
#include <hip/hip_runtime.h>
#include <hip/hip_bf16.h>

typedef unsigned short u16;
typedef unsigned int   u32;
typedef _Float16 f16;
typedef __attribute__((ext_vector_type(4))) float f32x4;
typedef __attribute__((ext_vector_type(8))) short s16x8;
typedef __attribute__((ext_vector_type(8))) f16 f16x8;
typedef __attribute__((ext_vector_type(2))) __fp16 fp16x2;
typedef __attribute__((ext_vector_type(4))) u16 u16x4;
typedef __attribute__((ext_vector_type(2))) u32 u32x2;

#define DI __device__ __forceinline__

static constexpr int Bb = 2, Ss = 2048, Hh = 16, Dd = 64, Ee = 1024;
static constexpr int Mrows = Bb * Ss;              // 4096
static constexpr size_t NE = (size_t)Mrows * Ee;   // 4 M elems
static constexpr size_t WN = (size_t)Ee * Ee;      // 1 M elems
static constexpr float QSCALE = 0.125f * 1.44269504088896f;  // 1/8 * log2(e)

DI float bf2f(u16 h) { u32 u = ((u32)h) << 16; return __builtin_bit_cast(float, u); }
DI u16 f2bf(float f) {
    u32 u = __builtin_bit_cast(u32, f);
    u32 r = (u + 0x7FFFu + ((u >> 16) & 1u)) >> 16;
    return (u16)r;
}
DI u16 f2h(float f) { f16 h = (f16)f; return __builtin_bit_cast(u16, h); }
DI u32 pkrtz(float a, float b) {
    fp16x2 r = __builtin_amdgcn_cvt_pkrtz(a, b);
    return __builtin_bit_cast(u32, r);
}
DI float ex2(float x) { return __builtin_amdgcn_exp2f(x); }

#define MFMA_BF(a, b, c) __builtin_amdgcn_mfma_f32_16x16x32_bf16((a), (b), (c), 0, 0, 0)
#define MFMA_F16(a, b, c) __builtin_amdgcn_mfma_f32_16x16x32_f16( \
    __builtin_bit_cast(f16x8, (a)), __builtin_bit_cast(f16x8, (b)), (c), 0, 0, 0)

// async global->LDS, 16B per lane (LDS dest must be lane-linear)
DI void gld16(const u16* g, u16* l) {
    __builtin_amdgcn_global_load_lds((const __attribute__((address_space(1))) void*)g,
                                     (__attribute__((address_space(3))) void*)l, 16, 0, 0);
}

// ---------------- prep: q,k -> bf16 hi/lo; v -> fp16 ----------------
__global__ __launch_bounds__(256) void k_split3(
    const float* __restrict__ q, const float* __restrict__ k, const float* __restrict__ v,
    u16* __restrict__ qh, u16* __restrict__ ql,
    u16* __restrict__ kh, u16* __restrict__ kl, u16* __restrict__ vh) {
    int i = blockIdx.x * 256 + threadIdx.x;
    int y = blockIdx.y;
    if (y == 2) { vh[i] = f2h(v[i]); return; }
    const float* s = y ? k : q;
    u16* h = y ? kh : qh;
    u16* l = y ? kl : ql;
    float val = s[i];
    u16 hh = f2bf(val);
    h[i] = hh;
    l[i] = f2bf(val - bf2f(hh));
}

// ---------------- prep: weights -> B^T [N][K] via LDS-tiled transpose ----------------
// y=0: Wq -> bf16 hi/lo; y=1: Wk -> bf16 hi/lo; y=2: Wv -> fp16; y=3: Wo -> fp16.
__global__ __launch_bounds__(256) void k_wprep(
    const float* __restrict__ Wq, const float* __restrict__ Wk,
    const float* __restrict__ Wv, const float* __restrict__ Wo,
    u16* __restrict__ WqTh, u16* __restrict__ WqTl,
    u16* __restrict__ WkTh, u16* __restrict__ WkTl,
    u16* __restrict__ WvT, u16* __restrict__ WoT) {
    __shared__ float Ts[64 * 65];
    const int y = blockIdx.y;
    const int ti = blockIdx.x >> 4, tj = blockIdx.x & 15;   // n-tile, k-tile
    const float* W = (y == 0) ? Wq : (y == 1) ? Wk : (y == 2) ? Wv : Wo;
    const int t = threadIdx.x;
    const int col = t & 63, rb = (t >> 6) * 16;
#pragma unroll
    for (int rr = 0; rr < 16; rr++) {
        int row = rb + rr;   // k-local
        float v = (y < 3) ? W[(size_t)ti * 65536 + (size_t)(tj * 64 + row) * 64 + col]
                          : W[(size_t)(tj * 64 + row) * Ee + ti * 64 + col];
        Ts[row * 65 + col] = v;
    }
    __syncthreads();
#pragma unroll
    for (int rr = 0; rr < 16; rr++) {
        int orow = rb + rr;  // n-local
        int ocol = col;      // k-local (coalesced)
        float v = Ts[ocol * 65 + orow];
        size_t oidx = (size_t)(ti * 64 + orow) * Ee + tj * 64 + ocol;
        if (y == 0) {
            u16 hh = f2bf(v); WqTh[oidx] = hh; WqTl[oidx] = f2bf(v - bf2f(hh));
        } else if (y == 1) {
            u16 hh = f2bf(v); WkTh[oidx] = hh; WkTl[oidx] = f2bf(v - bf2f(hh));
        } else if (y == 2) {
            WvT[oidx] = f2h(v);
        } else {
            WoT[oidx] = f2h(v);
        }
    }
}

// ---------------- GEMM body, 64(M) x 128(N) tile ----------------
// Retiled from 128x128 (round 7): staging bytes/MFMA 341->256, grid 2x ->
// ~5-6 blocks/CU so other blocks' waves cover each block's barrier drain
// (round-6 counters: Mfma 24 + VALU 23 = 47% busy, rest idle at 3 blocks/CU).
// SPLIT=1: bf16 hi/lo 3-MFMA. F16=1: fp16 MFMA.
// OUTMODE: 0 = f32 row-major, 1 = fp16 transposed [N][M], 2 = bf16 hi/lo row-major.
template <int SPLIT, int F16, int OUTMODE>
DI void gemm_body(const u16* __restrict__ Ah, const u16* __restrict__ Al,
                  const u16* __restrict__ Bh, const u16* __restrict__ Bl,
                  const float* __restrict__ bias,
                  u16* __restrict__ C16h, u16* __restrict__ C16l, float* __restrict__ Cf,
                  float scale, u16* As0, u16* As1, u16* Bs0, u16* Bs1) {
    constexpr int M = Mrows, N = Ee, K = Ee;
    const int tid = threadIdx.x;
    const int wave = tid >> 6, lane = tid & 63;
    const int quad = lane >> 4, l16 = lane & 15;
    const int m0 = blockIdx.y * 64, n0 = blockIdx.x * 128;
    const int wm = (wave >> 1) * 32, wn = (wave & 1) * 64;

    f32x4 acc[2][4];
#pragma unroll
    for (int i = 0; i < 2; i++)
#pragma unroll
        for (int j = 0; j < 4; j++) acc[i][j] = (f32x4)0.0f;

    for (int kk = 0; kk < K; kk += 32) {
        __syncthreads();
        {   // A tile: 64 rows x 32 k = 256 chunks of 16B (lane-linear)
            int c = tid;
            int row = c >> 2, j = c & 3;
            size_t ga = (size_t)(m0 + row) * K + kk + j * 8;
            gld16(Ah + ga, As0 + c * 8);
            if constexpr (SPLIT) gld16(Al + ga, As1 + c * 8);
        }
#pragma unroll
        for (int i = 0; i < 2; i++) {  // B tile: 128 rows x 32 k = 512 chunks
            int c = tid + i * 256;
            int row = c >> 2, j = c & 3;
            size_t gb = (size_t)(n0 + row) * K + kk + j * 8;
            gld16(Bh + gb, Bs0 + c * 8);
            if constexpr (SPLIT) gld16(Bl + gb, Bs1 + c * 8);
        }
        __syncthreads();

        s16x8 af[2][2], bf[4][2];
#pragma unroll
        for (int mt = 0; mt < 2; mt++) {
            int r = wm + mt * 16 + l16;
            af[mt][0] = *(const s16x8*)&As0[r * 32 + quad * 8];
            if constexpr (SPLIT) af[mt][1] = *(const s16x8*)&As1[r * 32 + quad * 8];
        }
#pragma unroll
        for (int nt = 0; nt < 4; nt++) {
            int r = wn + nt * 16 + l16;
            bf[nt][0] = *(const s16x8*)&Bs0[r * 32 + quad * 8];
            if constexpr (SPLIT) bf[nt][1] = *(const s16x8*)&Bs1[r * 32 + quad * 8];
        }
#pragma unroll
        for (int mt = 0; mt < 2; mt++)
#pragma unroll
            for (int nt = 0; nt < 4; nt++) {
                if constexpr (F16) {
                    acc[mt][nt] = MFMA_F16(af[mt][0], bf[nt][0], acc[mt][nt]);
                } else {
                    acc[mt][nt] = MFMA_BF(af[mt][0], bf[nt][0], acc[mt][nt]);
                    if constexpr (SPLIT) {
                        acc[mt][nt] = MFMA_BF(af[mt][0], bf[nt][1], acc[mt][nt]);
                        acc[mt][nt] = MFMA_BF(af[mt][1], bf[nt][0], acc[mt][nt]);
                    }
                }
            }
    }

    // epilogue — C/D layout: col = lane&15, row = quad*4 + reg
#pragma unroll
    for (int mt = 0; mt < 2; mt++)
#pragma unroll
        for (int nt = 0; nt < 4; nt++) {
            int gn = n0 + wn + nt * 16 + l16;
            float bs = bias[gn];
            if constexpr (OUTMODE == 1) {
                int gm = m0 + wm + mt * 16 + quad * 4;
                u16x4 pk;
#pragma unroll
                for (int r = 0; r < 4; r++) pk[r] = f2h((acc[mt][nt][r] + bs) * scale);
                *(u16x4*)&C16h[(size_t)gn * M + gm] = pk;
            } else {
#pragma unroll
                for (int r = 0; r < 4; r++) {
                    int gm = m0 + wm + mt * 16 + quad * 4 + r;
                    float v = (acc[mt][nt][r] + bs) * scale;
                    if constexpr (OUTMODE == 0) {
                        Cf[(size_t)gm * N + gn] = v;
                    } else {
                        u16 hh = f2bf(v);
                        C16h[(size_t)gm * N + gn] = hh;
                        C16l[(size_t)gm * N + gn] = f2bf(v - bf2f(hh));
                    }
                }
            }
        }
}

// ---------------- fused Q/K/V projections (grid.z selects) ----------------
__global__ __launch_bounds__(256, 4) void k_qkv(
    const u16* __restrict__ qh, const u16* __restrict__ ql,
    const u16* __restrict__ kh, const u16* __restrict__ kl,
    const u16* __restrict__ vh,
    const u16* __restrict__ WqTh, const u16* __restrict__ WqTl,
    const u16* __restrict__ WkTh, const u16* __restrict__ WkTl,
    const u16* __restrict__ WvT,
    const float* __restrict__ bq, const float* __restrict__ bk, const float* __restrict__ bv,
    u16* __restrict__ Qh, u16* __restrict__ Ql2,
    u16* __restrict__ Kh, u16* __restrict__ Kl2, u16* __restrict__ Vt) {
    __shared__ u16 As[2][64 * 32];
    __shared__ u16 Bs[2][128 * 32];
    int z = blockIdx.z;
    if (z == 0)
        gemm_body<1, 0, 2>(qh, ql, WqTh, WqTl, bq, Qh, Ql2, nullptr, QSCALE,
                           As[0], As[1], Bs[0], Bs[1]);
    else if (z == 1)
        gemm_body<1, 0, 2>(kh, kl, WkTh, WkTl, bk, Kh, Kl2, nullptr, 1.0f,
                           As[0], As[1], Bs[0], Bs[1]);
    else
        gemm_body<0, 1, 1>(vh, nullptr, WvT, nullptr, bv, Vt, nullptr, nullptr, 1.0f,
                           As[0], As[1], Bs[0], Bs[1]);
}

// ---------------- output projection: ctx(fp16) @ WoT(fp16) + bo -> f32 ----------------
__global__ __launch_bounds__(256, 4) void k_out(
    const u16* __restrict__ ctx, const u16* __restrict__ WoT,
    const float* __restrict__ bo, float* __restrict__ out) {
    __shared__ u16 As[64 * 32];
    __shared__ u16 Bs[128 * 32];
    gemm_body<0, 1, 0>(ctx, nullptr, WoT, nullptr, bo, nullptr, nullptr, out, 1.0f,
                       As, nullptr, Bs, nullptr);
}

// ---------------- flash attention, S^T formulation, 64-row q-tiles ----------------
// Score path: bf16 hi/lo split (QhKh + QhKl + QlKh) — required precision (round-5 lesson:
// fp16 scores give absmax ~432 via softmax near-tie flips; split-bf16 gives ~32).
// V/P/ctx path: fp16. Q pre-scaled by log2e/8; exp2-domain softmax.
// S^T[t][q] = K[t][:]·Q[q][:] (A=K LDS, B=Q regs); O^T[d][q] += V^T[d][t]·P^T[t][q].
__global__ __launch_bounds__(256, 4) void k_attn(
    const u16* __restrict__ Qh, const u16* __restrict__ Ql,
    const u16* __restrict__ Kh, const u16* __restrict__ Kl,
    const u16* __restrict__ Vt, u16* __restrict__ ctx) {
    const int bh = blockIdx.y;
    const int b = bh >> 4, h = bh & 15;
    const int q0 = blockIdx.x * 64;
    const int rowBase = b * Ss + q0;
    const int hc = h * 64;

    __shared__ u16 Ks[2][64 * 64];     // [t][d] bf16 hi/lo, xor-swizzled chunks
    __shared__ u16 Vs[64 * 64];        // [d][t] fp16, xor-swizzled chunks
    __shared__ u16 Ps[4][16 * 72];     // per-wave [qloc][t] fp16, padded row 72

    const int tid = threadIdx.x;
    const int wave = tid >> 6, lane = tid & 63;
    const int quad = lane >> 4, l16 = lane & 15;

    // loop-invariant Q B-frags bq[kc][hl] (lane n = q, k-contiguous 16B)
    s16x8 bq[2][2];
    {
        int row = rowBase + wave * 16 + l16;
#pragma unroll
        for (int kc = 0; kc < 2; kc++) {
            bq[kc][0] = *(const s16x8*)(Qh + (size_t)row * Ee + hc + kc * 32 + quad * 8);
            bq[kc][1] = *(const s16x8*)(Ql + (size_t)row * Ee + hc + kc * 32 + quad * 8);
        }
    }

    f32x4 o[4];
#pragma unroll
    for (int mt = 0; mt < 4; mt++) o[mt] = (f32x4)0.0f;
    float m_ = -1e30f, l_ = 0.f;

    for (int t0 = 0; t0 < Ss; t0 += 64) {
        const int kRowBase = b * Ss + t0;
        __syncthreads();
#pragma unroll
        for (int i = 0; i < 2; i++) {
            int c = tid + i * 256;
            int row = c >> 3, j = c & 7;
            int sj = j ^ (row & 7);
            *(s16x8*)&Ks[0][row * 64 + sj * 8] =
                *(const s16x8*)(Kh + (size_t)(kRowBase + row) * Ee + hc + j * 8);
            *(s16x8*)&Ks[1][row * 64 + sj * 8] =
                *(const s16x8*)(Kl + (size_t)(kRowBase + row) * Ee + hc + j * 8);
            *(s16x8*)&Vs[row * 64 + sj * 8] =
                *(const s16x8*)(Vt + (size_t)(hc + row) * Mrows + kRowBase + j * 8);
        }
        __syncthreads();

        // S^T = K·Q^T (split); st[mt], t = mt*16 + quad*4 + r, q-col = l16
        f32x4 st[4];
#pragma unroll
        for (int mt = 0; mt < 4; mt++) st[mt] = (f32x4)0.0f;
#pragma unroll
        for (int mt = 0; mt < 4; mt++) {
            int tr = mt * 16 + l16;
#pragma unroll
            for (int kc = 0; kc < 2; kc++) {
                int sj = (kc * 4 + quad) ^ (l16 & 7);
                s16x8 akh = *(const s16x8*)&Ks[0][tr * 64 + sj * 8];
                s16x8 akl = *(const s16x8*)&Ks[1][tr * 64 + sj * 8];
                st[mt] = MFMA_BF(akh, bq[kc][0], st[mt]);
                st[mt] = MFMA_BF(akh, bq[kc][1], st[mt]);
                st[mt] = MFMA_BF(akl, bq[kc][0], st[mt]);
            }
        }

        // online softmax per q-column (1 per lane), exp2 domain
        float t01 = fmaxf(fmaxf(st[0][0], st[0][1]), fmaxf(st[0][2], st[0][3]));
        float t23 = fmaxf(fmaxf(st[1][0], st[1][1]), fmaxf(st[1][2], st[1][3]));
        float t45 = fmaxf(fmaxf(st[2][0], st[2][1]), fmaxf(st[2][2], st[2][3]));
        float t67 = fmaxf(fmaxf(st[3][0], st[3][1]), fmaxf(st[3][2], st[3][3]));
        float tmax = fmaxf(fmaxf(t01, t23), fmaxf(t45, t67));
        tmax = fmaxf(tmax, __shfl_xor(tmax, 16));
        tmax = fmaxf(tmax, __shfl_xor(tmax, 32));
        float mnew = fmaxf(m_, tmax);
        float al = ex2(m_ - mnew);
        m_ = mnew;
        float psum = 0.f;
#pragma unroll
        for (int mt = 0; mt < 4; mt++) {
            float p0 = ex2(st[mt][0] - mnew);
            float p1 = ex2(st[mt][1] - mnew);
            float p2 = ex2(st[mt][2] - mnew);
            float p3 = ex2(st[mt][3] - mnew);
            psum += (p0 + p1) + (p2 + p3);
            u32x2 pk;
            pk[0] = pkrtz(p0, p1);
            pk[1] = pkrtz(p2, p3);
            *(u32x2*)&Ps[wave][l16 * 72 + mt * 16 + quad * 4] = pk;
        }
        psum += __shfl_xor(psum, 16);
        psum += __shfl_xor(psum, 32);
        l_ = l_ * al + psum;
#pragma unroll
        for (int mt = 0; mt < 4; mt++) o[mt] *= al;

        // O^T += V^T P^T  (A = Vs[d][t], B = Ps[q][t])
#pragma unroll
        for (int kc = 0; kc < 2; kc++) {
            s16x8 bp = *(const s16x8*)&Ps[wave][l16 * 72 + kc * 32 + quad * 8];
#pragma unroll
            for (int mt = 0; mt < 4; mt++) {
                int sj = (kc * 4 + quad) ^ (l16 & 7);
                s16x8 av = *(const s16x8*)&Vs[(mt * 16 + l16) * 64 + sj * 8];
                o[mt] = MFMA_F16(av, bp, o[mt]);
            }
        }
    }

    // epilogue: ctx[q][hc+d] fp16, d = mt*16 + quad*4 + r  -> 8B packed stores
    float inv = 1.0f / l_;
    int gm = rowBase + wave * 16 + l16;
#pragma unroll
    for (int mt = 0; mt < 4; mt++) {
        u32x2 pk;
        pk[0] = pkrtz(o[mt][0] * inv, o[mt][1] * inv);
        pk[1] = pkrtz(o[mt][2] * inv, o[mt][3] * inv);
        *(u32x2*)&ctx[(size_t)gm * Ee + hc + mt * 16 + quad * 4] = pk;
    }
}

extern "C" void kernel_launch(void* const* d_in, const int* in_sizes, int n_in,
                              void* d_out, int out_size, void* d_ws, size_t ws_size,
                              hipStream_t stream) {
    const float* q   = (const float*)d_in[0];
    const float* kin = (const float*)d_in[1];
    const float* v   = (const float*)d_in[2];
    const float* Wq  = (const float*)d_in[3];
    const float* Wk  = (const float*)d_in[4];
    const float* Wv  = (const float*)d_in[5];
    const float* bq  = (const float*)d_in[6];
    const float* bk  = (const float*)d_in[7];
    const float* bv  = (const float*)d_in[8];
    const float* Wo  = (const float*)d_in[9];
    const float* bo  = (const float*)d_in[10];

    u16* ws = (u16*)d_ws;
    u16 *qh = ws,          *ql = ws + NE,     *kh = ws + 2 * NE, *kl = ws + 3 * NE;
    u16 *vh = ws + 4 * NE;
    u16 *Qh = ws + 5 * NE, *Ql = ws + 6 * NE, *Kh = ws + 7 * NE, *Kl = ws + 8 * NE;
    u16 *Vt = ws + 9 * NE, *ctx = ws + 10 * NE;
    u16 *WqTh = ws + 11 * NE;
    u16 *WqTl = WqTh + WN, *WkTh = WqTh + 2 * WN, *WkTl = WqTh + 3 * WN;
    u16 *WvT = WqTh + 4 * WN, *WoT = WqTh + 5 * WN;

    dim3 b256(256);
    k_split3<<<dim3(NE / 256, 3), b256, 0, stream>>>(q, kin, v, qh, ql, kh, kl, vh);
    k_wprep<<<dim3(256, 4), b256, 0, stream>>>(Wq, Wk, Wv, Wo,
                                               WqTh, WqTl, WkTh, WkTl, WvT, WoT);

    k_qkv<<<dim3(8, 64, 3), b256, 0, stream>>>(qh, ql, kh, kl, vh,
                                               WqTh, WqTl, WkTh, WkTl, WvT,
                                               bq, bk, bv, Qh, Ql, Kh, Kl, Vt);

    k_attn<<<dim3(Ss / 64, Bb * Hh), b256, 0, stream>>>(Qh, Ql, Kh, Kl, Vt, ctx);

    k_out<<<dim3(8, 64), b256, 0, stream>>>(ctx, WoT, bo, (float*)d_out);
}